// Round 5
// baseline (104.060 us; speedup 1.0000x reference)
//
#include <hip/hip_runtime.h>

// Fused LSTM: B=4096, T=200, F=64, H=16, O=1.
// 16 batches per wave, batch = column axis (lane&15) of 16x16 MFMA tiles.
//   pre^T(64x16) = Wih(64x64) @ x_t^T + Whh(64x16) @ h^T + bias
// Gate-type m = D-tile m (i/f/g/o are 16-row blocks), so each lane holds
// i,f,g,o for the SAME 4 (batch,unit) pairs -> cell update is lane-local,
// and h[4] per lane is directly the next step's recurrence B-fragment
// (col=l15=batch, k=lhi*4+j=unit). No cross-lane ops in the time loop.
// Recurrence in error-compensated f16 (hi+lo split for both Whh and h).
// x prefetched 4 steps ahead in a register ring (static slot indices).

#define Bsz 4096
#define Tn  200
#define Fn  64
#define Hn  16

typedef _Float16 half8  __attribute__((ext_vector_type(8)));
typedef _Float16 half4  __attribute__((ext_vector_type(4)));
typedef float    f32x4  __attribute__((ext_vector_type(4)));

__device__ __forceinline__ half8 to_half8(const float4& a, const float4& b) {
    half8 h;
    h[0] = (_Float16)a.x; h[1] = (_Float16)a.y; h[2] = (_Float16)a.z; h[3] = (_Float16)a.w;
    h[4] = (_Float16)b.x; h[5] = (_Float16)b.y; h[6] = (_Float16)b.z; h[7] = (_Float16)b.w;
    return h;
}

__device__ __forceinline__ float sigm(float z) {
    // 1 / (1 + 2^(-z*log2e))
    return __builtin_amdgcn_rcpf(1.0f + __builtin_amdgcn_exp2f(z * -1.4426950408889634f));
}
__device__ __forceinline__ float tanhp(float z) {
    // 2 / (1 + 2^(-2z*log2e)) - 1
    return fmaf(2.0f, __builtin_amdgcn_rcpf(
        1.0f + __builtin_amdgcn_exp2f(z * -2.8853900817779268f)), -1.0f);
}

__global__ __launch_bounds__(64, 1) void lstm_fused(
    const float* __restrict__ x,     // [B, T, F]
    const float* __restrict__ Wih,   // [64, 64]
    const float* __restrict__ Whh,   // [64, 16]
    const float* __restrict__ bih,   // [64]
    const float* __restrict__ bhh,   // [64]
    const float* __restrict__ Wout,  // [1, 16]
    const float* __restrict__ bout,  // [1]
    float* __restrict__ out)         // [B, 1]
{
    const int lane = threadIdx.x & 63;
    const int l15  = lane & 15;
    const int lhi  = lane >> 4;
    const int b    = (int)blockIdx.x * 16 + l15;   // per-lane batch

    // ---- Wih A-fragments (16x16x32): tile m row = gate 16m+l15, k = kh*32+lhi*8+j
    half8 WihF[4][2];
#pragma unroll
    for (int m = 0; m < 4; ++m)
#pragma unroll
        for (int kh = 0; kh < 2; ++kh) {
            const float* wr = Wih + (m * 16 + l15) * Fn + kh * 32 + lhi * 8;
            float4 w0 = *reinterpret_cast<const float4*>(wr);
            float4 w1 = *reinterpret_cast<const float4*>(wr + 4);
            WihF[m][kh] = to_half8(w0, w1);
        }

    // ---- Whh A-fragments (16x16x16), hi/lo error-compensated:
    //      tile m row = gate 16m+l15, k = lhi*4+j (unit)
    half4 WhhHi[4], WhhLo[4];
#pragma unroll
    for (int m = 0; m < 4; ++m) {
        float4 w = *reinterpret_cast<const float4*>(Whh + (m * 16 + l15) * Hn + lhi * 4);
        float wv[4] = { w.x, w.y, w.z, w.w };
#pragma unroll
        for (int j = 0; j < 4; ++j) {
            _Float16 hi = (_Float16)wv[j];
            WhhHi[m][j] = hi;
            WhhLo[m][j] = (_Float16)(wv[j] - (float)hi);
        }
    }

    // ---- bias as MFMA C-init: tile m, lane rows = gates 16m + lhi*4 + r
    f32x4 biasC[4];
#pragma unroll
    for (int m = 0; m < 4; ++m) {
        float4 v0 = *reinterpret_cast<const float4*>(bih + m * 16 + lhi * 4);
        float4 v1 = *reinterpret_cast<const float4*>(bhh + m * 16 + lhi * 4);
        biasC[m][0] = v0.x + v1.x; biasC[m][1] = v0.y + v1.y;
        biasC[m][2] = v0.z + v1.z; biasC[m][3] = v0.w + v1.w;
    }

    // per-lane x pointer: batch b, feats lhi*8 + {0..7, 32..39} per step
    const float* xl = x + (size_t)b * (Tn * Fn) + lhi * 8;

    // ---- x register ring: slot s holds step (consumed in slot order)
    float4 ring[4][4];
#pragma unroll
    for (int s = 0; s < 4; ++s) {
        const float* xp = xl + s * Fn;
        ring[s][0] = *reinterpret_cast<const float4*>(xp);
        ring[s][1] = *reinterpret_cast<const float4*>(xp + 4);
        ring[s][2] = *reinterpret_cast<const float4*>(xp + 32);
        ring[s][3] = *reinterpret_cast<const float4*>(xp + 36);
    }

    // ---- state: per lane, batch l15, units lhi*4 + {0..3}
    f32x4 cst = { 0.0f, 0.0f, 0.0f, 0.0f };
    half4 hHi = { 0, 0, 0, 0 }, hLo = { 0, 0, 0, 0 };
    float hcur[4] = { 0.0f, 0.0f, 0.0f, 0.0f };
    f32x4 gxA[4], gxB[4];

    // input projection for one step from ring slot rs -> gxn; reload rs
    auto proj = [&](float4 (&rs)[4], f32x4 (&gxn)[4], int tload) {
        half8 f0 = to_half8(rs[0], rs[1]);   // B frag kh=0: feats lhi*8+0..7
        half8 f1 = to_half8(rs[2], rs[3]);   // kh=1: feats 32+lhi*8+0..7
#pragma unroll
        for (int m = 0; m < 4; ++m) {
            gxn[m] = __builtin_amdgcn_mfma_f32_16x16x32_f16(WihF[m][0], f0, biasC[m], 0, 0, 0);
            gxn[m] = __builtin_amdgcn_mfma_f32_16x16x32_f16(WihF[m][1], f1, gxn[m], 0, 0, 0);
        }
        const float* xp = xl + (size_t)tload * Fn;
        rs[0] = *reinterpret_cast<const float4*>(xp);
        rs[1] = *reinterpret_cast<const float4*>(xp + 4);
        rs[2] = *reinterpret_cast<const float4*>(xp + 32);
        rs[3] = *reinterpret_cast<const float4*>(xp + 36);
    };

    // one recurrence + cell step consuming gxc (= gx[t])
    auto recur = [&](f32x4 (&gxc)[4]) {
        f32x4 pre[4];
#pragma unroll
        for (int m = 0; m < 4; ++m) {
            pre[m] = __builtin_amdgcn_mfma_f32_16x16x16f16(WhhHi[m], hHi, gxc[m], 0, 0, 0);
            pre[m] = __builtin_amdgcn_mfma_f32_16x16x16f16(WhhLo[m], hHi, pre[m], 0, 0, 0);
            pre[m] = __builtin_amdgcn_mfma_f32_16x16x16f16(WhhHi[m], hLo, pre[m], 0, 0, 0);
        }
        // tile 0=i, 1=f, 2=g, 3=o; row r -> unit lhi*4+r, col l15 -> batch
#pragma unroll
        for (int r = 0; r < 4; ++r) {
            float ig = sigm(pre[0][r]);
            float fg = sigm(pre[1][r]);
            float gg = tanhp(pre[2][r]);
            float og = sigm(pre[3][r]);
            cst[r]  = fmaf(fg, cst[r], ig * gg);
            hcur[r] = og * tanhp(cst[r]);
        }
        // pack h -> f16 hi/lo fragments (B-frag layout for next step)
#pragma unroll
        for (int r = 0; r < 4; ++r) {
            _Float16 hi = (_Float16)hcur[r];
            hHi[r] = hi;
            hLo[r] = (_Float16)(hcur[r] - (float)hi);
        }
    };

    // prologue: gx[0] from slot 0; reload slot 0 with x[4]
    proj(ring[0], gxA, 4);

    // steps t..t+3 per iteration; step s consumes ring[(s+1)&3] = x[s+1]
#pragma unroll 1
    for (int t = 0; t < 196; t += 4) {
        int u = t + 5;
        int u0 = u     > 199 ? 199 : u;
        int u1 = u + 1 > 199 ? 199 : u + 1;
        int u2 = u + 2 > 199 ? 199 : u + 2;
        proj(ring[1], gxB, u0); recur(gxA);        // step t
        proj(ring[2], gxA, u1); recur(gxB);        // step t+1
        proj(ring[3], gxB, u2); recur(gxA);        // step t+2
        proj(ring[0], gxA, u + 3 > 199 ? 199 : u + 3); recur(gxB);  // t+3
    }
    // steps 196..199
    proj(ring[1], gxB, 199); recur(gxA);           // 196
    proj(ring[2], gxA, 199); recur(gxB);           // 197
    proj(ring[3], gxB, 199); recur(gxA);           // 198 (makes gx[199])
    recur(gxB);                                    // 199

    // final Linear(16->1) + sigmoid: partial over my 4 units, reduce over lhi
    float4 wo = *reinterpret_cast<const float4*>(Wout + lhi * 4);
    float po = hcur[0] * wo.x;
    po = fmaf(hcur[1], wo.y, po);
    po = fmaf(hcur[2], wo.z, po);
    po = fmaf(hcur[3], wo.w, po);
    po += __shfl_xor(po, 16);
    po += __shfl_xor(po, 32);
    if (lhi == 0)
        out[b] = sigm(po + bout[0]);
}

extern "C" void kernel_launch(void* const* d_in, const int* in_sizes, int n_in,
                              void* d_out, int out_size, void* d_ws, size_t ws_size,
                              hipStream_t stream) {
    const float* x    = (const float*)d_in[0];
    const float* Wih  = (const float*)d_in[1];
    const float* Whh  = (const float*)d_in[2];
    const float* bih  = (const float*)d_in[3];
    const float* bhh  = (const float*)d_in[4];
    const float* Wout = (const float*)d_in[5];
    const float* bout = (const float*)d_in[6];
    float* out = (float*)d_out;

    lstm_fused<<<dim3(Bsz / 16), dim3(64), 0, stream>>>(
        x, Wih, Whh, bih, bhh, Wout, bout, out);
}

// Round 6
// 86.356 us; speedup vs baseline: 1.2050x; 1.2050x over previous
//
#include <hip/hip_runtime.h>

// Fused LSTM: B=4096, T=200, F=64, H=16, O=1.
// Producer/consumer decoupling, 2 waves per block, 16 batches per block.
//   pre^T(64x16) = Wih(64x64) @ x_t^T + Whh(64x16) @ h^T + bias
// Producer wave: loads x (8-step register stage, 1 chunk ahead) and runs the
// input projection on MFMA (bias folded into C), writing gx f32x4 tiles into
// a 3-deep LDS ring of 8-step chunks. Consumer wave: per step reads gx
// (prefetched 1 step ahead), does the serial recurrence (3 compensated f16
// MFMAs) + lane-local cell update. Gate-type m = D-tile m, so each lane holds
// i,f,g,o of the SAME 4 (batch,unit) pairs, and its h[4] is directly the next
// step's recurrence B-fragment -> zero cross-lane ops in the chain.
// Producer D-layout == consumer read layout -> no transpose in LDS.

#define Bsz 4096
#define Tn  200
#define Fn  64
#define Hn  16
#define CS  8     // steps per chunk
#define NCH 25    // chunks (25*8 = 200)

typedef _Float16 half8  __attribute__((ext_vector_type(8)));
typedef _Float16 half4  __attribute__((ext_vector_type(4)));
typedef float    f32x4  __attribute__((ext_vector_type(4)));

__device__ __forceinline__ half8 to_half8(const float4& a, const float4& b) {
    half8 h;
    h[0] = (_Float16)a.x; h[1] = (_Float16)a.y; h[2] = (_Float16)a.z; h[3] = (_Float16)a.w;
    h[4] = (_Float16)b.x; h[5] = (_Float16)b.y; h[6] = (_Float16)b.z; h[7] = (_Float16)b.w;
    return h;
}

__device__ __forceinline__ float sigm(float z) {
    return __builtin_amdgcn_rcpf(1.0f + __builtin_amdgcn_exp2f(z * -1.4426950408889634f));
}
__device__ __forceinline__ float tanhp(float z) {
    return fmaf(2.0f, __builtin_amdgcn_rcpf(
        1.0f + __builtin_amdgcn_exp2f(z * -2.8853900817779268f)), -1.0f);
}

__global__ __launch_bounds__(128, 1) void lstm_fused(
    const float* __restrict__ x,     // [B, T, F]
    const float* __restrict__ Wih,   // [64, 64]
    const float* __restrict__ Whh,   // [64, 16]
    const float* __restrict__ bih,   // [64]
    const float* __restrict__ bhh,   // [64]
    const float* __restrict__ Wout,  // [1, 16]
    const float* __restrict__ bout,  // [1]
    float* __restrict__ out)         // [B, 1]
{
    const int lane = threadIdx.x & 63;
    const int wave = threadIdx.x >> 6;   // 0 = consumer, 1 = producer
    const int l15  = lane & 15;
    const int lhi  = lane >> 4;
    const int b    = (int)blockIdx.x * 16 + l15;   // per-lane batch

    // gx ring: [buf][step][gate-tile m][lane] f32x4 = 3*8*4*64*16 B = 96 KiB
    __shared__ f32x4 gxbuf[3][CS][4][64];

    // ================= producer-side constants =================
    half8 WihF[4][2];
    f32x4 biasC[4];
    float4 xr[CS][4];          // x register stage for one chunk
    const float* xl = x + (size_t)b * (Tn * Fn) + lhi * 8;

    if (wave == 1) {
#pragma unroll
        for (int m = 0; m < 4; ++m)
#pragma unroll
            for (int kh = 0; kh < 2; ++kh) {
                const float* wr = Wih + (m * 16 + l15) * Fn + kh * 32 + lhi * 8;
                float4 w0 = *reinterpret_cast<const float4*>(wr);
                float4 w1 = *reinterpret_cast<const float4*>(wr + 4);
                WihF[m][kh] = to_half8(w0, w1);
            }
#pragma unroll
        for (int m = 0; m < 4; ++m) {
            float4 v0 = *reinterpret_cast<const float4*>(bih + m * 16 + lhi * 4);
            float4 v1 = *reinterpret_cast<const float4*>(bhh + m * 16 + lhi * 4);
            biasC[m][0] = v0.x + v1.x; biasC[m][1] = v0.y + v1.y;
            biasC[m][2] = v0.z + v1.z; biasC[m][3] = v0.w + v1.w;
        }
        // prologue: stage chunk 0
#pragma unroll
        for (int s = 0; s < CS; ++s) {
            const float* xp = xl + s * Fn;
            xr[s][0] = *reinterpret_cast<const float4*>(xp);
            xr[s][1] = *reinterpret_cast<const float4*>(xp + 4);
            xr[s][2] = *reinterpret_cast<const float4*>(xp + 32);
            xr[s][3] = *reinterpret_cast<const float4*>(xp + 36);
        }
    }

    // ================= consumer-side constants =================
    half4 WhhHi[4], WhhLo[4];
#pragma unroll
    for (int m = 0; m < 4; ++m) {
        float4 w = *reinterpret_cast<const float4*>(Whh + (m * 16 + l15) * Hn + lhi * 4);
        float wv[4] = { w.x, w.y, w.z, w.w };
#pragma unroll
        for (int j = 0; j < 4; ++j) {
            _Float16 hi = (_Float16)wv[j];
            WhhHi[m][j] = hi;
            WhhLo[m][j] = (_Float16)(wv[j] - (float)hi);
        }
    }

    f32x4 cst = { 0.0f, 0.0f, 0.0f, 0.0f };
    half4 hHi = { 0, 0, 0, 0 }, hLo = { 0, 0, 0, 0 };
    float hcur[4] = { 0.0f, 0.0f, 0.0f, 0.0f };

    // one recurrence + cell step consuming gx tiles g[0..3]
    auto recur = [&](f32x4 (&g)[4]) {
        f32x4 pre[4];
#pragma unroll
        for (int m = 0; m < 4; ++m) {
            pre[m] = __builtin_amdgcn_mfma_f32_16x16x16f16(WhhHi[m], hHi, g[m], 0, 0, 0);
            pre[m] = __builtin_amdgcn_mfma_f32_16x16x16f16(WhhLo[m], hHi, pre[m], 0, 0, 0);
            pre[m] = __builtin_amdgcn_mfma_f32_16x16x16f16(WhhHi[m], hLo, pre[m], 0, 0, 0);
        }
#pragma unroll
        for (int r = 0; r < 4; ++r) {
            float ig = sigm(pre[0][r]);
            float fg = sigm(pre[1][r]);
            float gg = tanhp(pre[2][r]);
            float og = sigm(pre[3][r]);
            cst[r]  = fmaf(fg, cst[r], ig * gg);
            hcur[r] = og * tanhp(cst[r]);
        }
#pragma unroll
        for (int r = 0; r < 4; ++r) {
            _Float16 hi = (_Float16)hcur[r];
            hHi[r] = hi;
            hLo[r] = (_Float16)(hcur[r] - (float)hi);
        }
    };

    // ================= pipelined main loop =================
#pragma unroll 1
    for (int i = 0; i < NCH + 2; ++i) {
        __syncthreads();
        if (wave == 1) {
            // -------- producer: compute gx chunk i, then stage chunk i+1
            if (i < NCH) {
                const int bi = i % 3;
#pragma unroll
                for (int s = 0; s < CS; ++s) {
                    half8 f0 = to_half8(xr[s][0], xr[s][1]);
                    half8 f1 = to_half8(xr[s][2], xr[s][3]);
#pragma unroll
                    for (int m = 0; m < 4; ++m) {
                        f32x4 acc = __builtin_amdgcn_mfma_f32_16x16x32_f16(
                            WihF[m][0], f0, biasC[m], 0, 0, 0);
                        acc = __builtin_amdgcn_mfma_f32_16x16x32_f16(
                            WihF[m][1], f1, acc, 0, 0, 0);
                        gxbuf[bi][s][m][lane] = acc;
                    }
                }
                if (i + 1 < NCH) {
                    const float* xc = xl + (size_t)(i + 1) * (CS * Fn);
#pragma unroll
                    for (int s = 0; s < CS; ++s) {
                        const float* xp = xc + s * Fn;
                        xr[s][0] = *reinterpret_cast<const float4*>(xp);
                        xr[s][1] = *reinterpret_cast<const float4*>(xp + 4);
                        xr[s][2] = *reinterpret_cast<const float4*>(xp + 32);
                        xr[s][3] = *reinterpret_cast<const float4*>(xp + 36);
                    }
                }
            }
        } else {
            // -------- consumer: recurrence over chunk i-2
            if (i >= 2) {
                const int bi = (i - 2) % 3;
                f32x4 gA[4], gB[4];
#pragma unroll
                for (int m = 0; m < 4; ++m) gA[m] = gxbuf[bi][0][m][lane];
#pragma unroll
                for (int m = 0; m < 4; ++m) gB[m] = gxbuf[bi][1][m][lane];
                recur(gA);
#pragma unroll
                for (int m = 0; m < 4; ++m) gA[m] = gxbuf[bi][2][m][lane];
                recur(gB);
#pragma unroll
                for (int m = 0; m < 4; ++m) gB[m] = gxbuf[bi][3][m][lane];
                recur(gA);
#pragma unroll
                for (int m = 0; m < 4; ++m) gA[m] = gxbuf[bi][4][m][lane];
                recur(gB);
#pragma unroll
                for (int m = 0; m < 4; ++m) gB[m] = gxbuf[bi][5][m][lane];
                recur(gA);
#pragma unroll
                for (int m = 0; m < 4; ++m) gA[m] = gxbuf[bi][6][m][lane];
                recur(gB);
#pragma unroll
                for (int m = 0; m < 4; ++m) gB[m] = gxbuf[bi][7][m][lane];
                recur(gA);
                recur(gB);
            }
        }
    }

    // ================= epilogue: Linear(16->1) + sigmoid =================
    if (wave == 0) {
        float4 wo = *reinterpret_cast<const float4*>(Wout + lhi * 4);
        float po = hcur[0] * wo.x;
        po = fmaf(hcur[1], wo.y, po);
        po = fmaf(hcur[2], wo.z, po);
        po = fmaf(hcur[3], wo.w, po);
        po += __shfl_xor(po, 16);
        po += __shfl_xor(po, 32);
        if (lhi == 0)
            out[b] = sigm(po + bout[0]);
    }
}

extern "C" void kernel_launch(void* const* d_in, const int* in_sizes, int n_in,
                              void* d_out, int out_size, void* d_ws, size_t ws_size,
                              hipStream_t stream) {
    const float* x    = (const float*)d_in[0];
    const float* Wih  = (const float*)d_in[1];
    const float* Whh  = (const float*)d_in[2];
    const float* bih  = (const float*)d_in[3];
    const float* bhh  = (const float*)d_in[4];
    const float* Wout = (const float*)d_in[5];
    const float* bout = (const float*)d_in[6];
    float* out = (float*)d_out;

    lstm_fused<<<dim3(Bsz / 16), dim3(128), 0, stream>>>(
        x, Wih, Whh, bih, bhh, Wout, bout, out);
}

// Round 7
// 73.714 us; speedup vs baseline: 1.4117x; 1.1715x over previous
//
#include <hip/hip_runtime.h>

// Fused LSTM: B=4096, T=200, F=64, H=16, O=1.
// Producer/consumer, 3 waves/block (1 consumer + 2 producers), 16 batches/block.
//   pre^T(64x16) = Wih(64x64) @ x_t^T + Whh(64x16) @ h^T + bias
// Producers: load x (4 steps each per 8-step chunk, register-staged 1 chunk
// ahead) and run the input projection on MFMA (bias folded into C), writing
// gx f32x4 tiles into a 3-deep LDS ring. Consumer: per step, one
// mfma_16x16x16f16(WhhHi, hHi, gx) recurrence (uncompensated f16 -- error
// ~1e-4 RMS/step, AR(1)-damped by forget gate) + lane-local cell update.
// Gate-type m = D-tile m, so each lane holds i,f,g,o of the SAME 4
// (batch,unit) pairs, and its h[4] is directly the next step's recurrence
// B-fragment -> zero cross-lane ops in the serial chain.

#define Bsz 4096
#define Tn  200
#define Fn  64
#define Hn  16
#define CS  8     // steps per chunk
#define NCH 25    // chunks (25*8 = 200)

typedef _Float16 half8  __attribute__((ext_vector_type(8)));
typedef _Float16 half4  __attribute__((ext_vector_type(4)));
typedef float    f32x4  __attribute__((ext_vector_type(4)));

__device__ __forceinline__ half8 to_half8(const float4& a, const float4& b) {
    half8 h;
    h[0] = (_Float16)a.x; h[1] = (_Float16)a.y; h[2] = (_Float16)a.z; h[3] = (_Float16)a.w;
    h[4] = (_Float16)b.x; h[5] = (_Float16)b.y; h[6] = (_Float16)b.z; h[7] = (_Float16)b.w;
    return h;
}

__device__ __forceinline__ float sigm(float z) {
    return __builtin_amdgcn_rcpf(1.0f + __builtin_amdgcn_exp2f(z * -1.4426950408889634f));
}
__device__ __forceinline__ float tanhp(float z) {
    return fmaf(2.0f, __builtin_amdgcn_rcpf(
        1.0f + __builtin_amdgcn_exp2f(z * -2.8853900817779268f)), -1.0f);
}

__global__ __launch_bounds__(192, 1) void lstm_fused(
    const float* __restrict__ x,     // [B, T, F]
    const float* __restrict__ Wih,   // [64, 64]
    const float* __restrict__ Whh,   // [64, 16]
    const float* __restrict__ bih,   // [64]
    const float* __restrict__ bhh,   // [64]
    const float* __restrict__ Wout,  // [1, 16]
    const float* __restrict__ bout,  // [1]
    float* __restrict__ out)         // [B, 1]
{
    const int lane = threadIdx.x & 63;
    const int wave = threadIdx.x >> 6;   // 0 = consumer, 1/2 = producers
    const int l15  = lane & 15;
    const int lhi  = lane >> 4;
    const int b    = (int)blockIdx.x * 16 + l15;   // per-lane batch

    // gx ring: [buf][step][gate-tile m][lane] f32x4 = 3*8*4*64*16 B = 96 KiB
    __shared__ f32x4 gxbuf[3][CS][4][64];

    // ================= producer-side state =================
    half8 WihF[4][2];
    f32x4 biasC[4];
    float4 xr[4][4];                       // 4 staged steps per producer
    const int pofs = (wave - 1) * 4;       // this producer's step offset
    const float* xl = x + (size_t)b * (Tn * Fn) + lhi * 8;

    if (wave >= 1) {
#pragma unroll
        for (int m = 0; m < 4; ++m)
#pragma unroll
            for (int kh = 0; kh < 2; ++kh) {
                const float* wr = Wih + (m * 16 + l15) * Fn + kh * 32 + lhi * 8;
                float4 w0 = *reinterpret_cast<const float4*>(wr);
                float4 w1 = *reinterpret_cast<const float4*>(wr + 4);
                WihF[m][kh] = to_half8(w0, w1);
            }
#pragma unroll
        for (int m = 0; m < 4; ++m) {
            float4 v0 = *reinterpret_cast<const float4*>(bih + m * 16 + lhi * 4);
            float4 v1 = *reinterpret_cast<const float4*>(bhh + m * 16 + lhi * 4);
            biasC[m][0] = v0.x + v1.x; biasC[m][1] = v0.y + v1.y;
            biasC[m][2] = v0.z + v1.z; biasC[m][3] = v0.w + v1.w;
        }
        // prologue: stage my 4 steps of chunk 0
#pragma unroll
        for (int s = 0; s < 4; ++s) {
            const float* xp = xl + (pofs + s) * Fn;
            xr[s][0] = *reinterpret_cast<const float4*>(xp);
            xr[s][1] = *reinterpret_cast<const float4*>(xp + 4);
            xr[s][2] = *reinterpret_cast<const float4*>(xp + 32);
            xr[s][3] = *reinterpret_cast<const float4*>(xp + 36);
        }
    }

    // ================= consumer-side state =================
    half4 WhhHi[4];
#pragma unroll
    for (int m = 0; m < 4; ++m) {
        float4 w = *reinterpret_cast<const float4*>(Whh + (m * 16 + l15) * Hn + lhi * 4);
        WhhHi[m][0] = (_Float16)w.x; WhhHi[m][1] = (_Float16)w.y;
        WhhHi[m][2] = (_Float16)w.z; WhhHi[m][3] = (_Float16)w.w;
    }

    f32x4 cst = { 0.0f, 0.0f, 0.0f, 0.0f };
    half4 hHi = { 0, 0, 0, 0 };
    float hcur[4] = { 0.0f, 0.0f, 0.0f, 0.0f };

    // one recurrence + cell step consuming gx tiles g[0..3]
    auto recur = [&](f32x4 (&g)[4]) {
        f32x4 pre[4];
#pragma unroll
        for (int m = 0; m < 4; ++m)
            pre[m] = __builtin_amdgcn_mfma_f32_16x16x16f16(WhhHi[m], hHi, g[m], 0, 0, 0);
#pragma unroll
        for (int r = 0; r < 4; ++r) {
            float ig = sigm(pre[0][r]);
            float fg = sigm(pre[1][r]);
            float gg = tanhp(pre[2][r]);
            float og = sigm(pre[3][r]);
            cst[r]  = fmaf(fg, cst[r], ig * gg);
            hcur[r] = og * tanhp(cst[r]);
        }
#pragma unroll
        for (int r = 0; r < 4; ++r)
            hHi[r] = (_Float16)hcur[r];
    };

    // ================= pipelined main loop =================
#pragma unroll 1
    for (int i = 0; i < NCH + 2; ++i) {
        __syncthreads();
        if (wave >= 1) {
            // ---- producers: compute my 4 steps of chunk i, stage chunk i+1
            if (i < NCH) {
                const int bi = i % 3;
#pragma unroll
                for (int s = 0; s < 4; ++s) {
                    half8 f0 = to_half8(xr[s][0], xr[s][1]);
                    half8 f1 = to_half8(xr[s][2], xr[s][3]);
#pragma unroll
                    for (int m = 0; m < 4; ++m) {
                        f32x4 acc = __builtin_amdgcn_mfma_f32_16x16x32_f16(
                            WihF[m][0], f0, biasC[m], 0, 0, 0);
                        acc = __builtin_amdgcn_mfma_f32_16x16x32_f16(
                            WihF[m][1], f1, acc, 0, 0, 0);
                        gxbuf[bi][pofs + s][m][lane] = acc;
                    }
                }
                if (i + 1 < NCH) {
                    const float* xc = xl + (size_t)((i + 1) * CS + pofs) * Fn;
#pragma unroll
                    for (int s = 0; s < 4; ++s) {
                        const float* xp = xc + s * Fn;
                        xr[s][0] = *reinterpret_cast<const float4*>(xp);
                        xr[s][1] = *reinterpret_cast<const float4*>(xp + 4);
                        xr[s][2] = *reinterpret_cast<const float4*>(xp + 32);
                        xr[s][3] = *reinterpret_cast<const float4*>(xp + 36);
                    }
                }
            }
        } else {
            // ---- consumer: recurrence over chunk i-2
            if (i >= 2) {
                const int bi = (i - 2) % 3;
                f32x4 gA[4], gB[4];
#pragma unroll
                for (int m = 0; m < 4; ++m) gA[m] = gxbuf[bi][0][m][lane];
#pragma unroll
                for (int m = 0; m < 4; ++m) gB[m] = gxbuf[bi][1][m][lane];
                recur(gA);
#pragma unroll
                for (int m = 0; m < 4; ++m) gA[m] = gxbuf[bi][2][m][lane];
                recur(gB);
#pragma unroll
                for (int m = 0; m < 4; ++m) gB[m] = gxbuf[bi][3][m][lane];
                recur(gA);
#pragma unroll
                for (int m = 0; m < 4; ++m) gA[m] = gxbuf[bi][4][m][lane];
                recur(gB);
#pragma unroll
                for (int m = 0; m < 4; ++m) gB[m] = gxbuf[bi][5][m][lane];
                recur(gA);
#pragma unroll
                for (int m = 0; m < 4; ++m) gA[m] = gxbuf[bi][6][m][lane];
                recur(gB);
#pragma unroll
                for (int m = 0; m < 4; ++m) gB[m] = gxbuf[bi][7][m][lane];
                recur(gA);
                recur(gB);
            }
        }
    }

    // ================= epilogue: Linear(16->1) + sigmoid =================
    if (wave == 0) {
        float4 wo = *reinterpret_cast<const float4*>(Wout + lhi * 4);
        float po = hcur[0] * wo.x;
        po = fmaf(hcur[1], wo.y, po);
        po = fmaf(hcur[2], wo.z, po);
        po = fmaf(hcur[3], wo.w, po);
        po += __shfl_xor(po, 16);
        po += __shfl_xor(po, 32);
        if (lhi == 0)
            out[b] = sigm(po + bout[0]);
    }
}

extern "C" void kernel_launch(void* const* d_in, const int* in_sizes, int n_in,
                              void* d_out, int out_size, void* d_ws, size_t ws_size,
                              hipStream_t stream) {
    const float* x    = (const float*)d_in[0];
    const float* Wih  = (const float*)d_in[1];
    const float* Whh  = (const float*)d_in[2];
    const float* bih  = (const float*)d_in[3];
    const float* bhh  = (const float*)d_in[4];
    const float* Wout = (const float*)d_in[5];
    const float* bout = (const float*)d_in[6];
    float* out = (float*)d_out;

    lstm_fused<<<dim3(Bsz / 16), dim3(192), 0, stream>>>(
        x, Wih, Whh, bih, bhh, Wout, bout, out);
}